// Round 1
// baseline (1219.423 us; speedup 1.0000x reference)
//
#include <hip/hip_runtime.h>
#include <math.h>

// Problem constants
#define BB 2
#define SS 2048
#define DD 1024
#define HH 16
#define HD 64
#define MM (BB * SS)   // 4096 rows

// ---------------------------------------------------------------------------
// Tiled fp32 GEMM:  C = A[M x D] @ W[D x D] + bias
//   MODE 0: store permuted into [B, H, S, HD]  (for Q/K/V)
//   MODE 1: store plain  [M, D]                (attn output proj -> d_out)
// 128x128 tile, BK=16, 256 threads, 8x8 micro-tile, register prefetch.
// ---------------------------------------------------------------------------
template <int MODE>
__global__ __launch_bounds__(256) void sgemm_kernel(
    const float* __restrict__ A, const float* __restrict__ W,
    const float* __restrict__ bias, float* __restrict__ C)
{
    __shared__ float As[16][132];   // [k][m], pad 132 -> 16B-aligned rows, free reads
    __shared__ float Bs[16][128];   // [k][n]

    const int tid = threadIdx.x;
    const int tx = tid & 15;        // col-chunk 0..15
    const int ty = tid >> 4;        // row-chunk 0..15
    const int n0 = blockIdx.x * 128;
    const int m0 = blockIdx.y * 128;

    // global-load slot decomposition
    const int arow = tid >> 2;      // 0..63
    const int ak4  = tid & 3;       // 0..3 (float4 within the 16-wide k strip)
    const int brow = tid >> 5;      // 0..7
    const int bc4  = tid & 31;      // 0..31

    const float* Aptr = A + (size_t)m0 * DD;

    float acc[8][8];
#pragma unroll
    for (int i = 0; i < 8; ++i)
#pragma unroll
        for (int j = 0; j < 8; ++j) acc[i][j] = 0.f;

    float4 pa[2], pb[2];
    // prologue: stage k0 = 0
#pragma unroll
    for (int s2 = 0; s2 < 2; ++s2) {
        pa[s2] = *(const float4*)&Aptr[(size_t)(arow + s2 * 64) * DD + ak4 * 4];
        pb[s2] = *(const float4*)&W[(size_t)(brow + s2 * 8) * DD + n0 + bc4 * 4];
    }

    for (int kt = 0; kt < 64; ++kt) {
        // commit staged regs to LDS (A transposed)
#pragma unroll
        for (int s2 = 0; s2 < 2; ++s2) {
            const int row = arow + s2 * 64;
            As[ak4 * 4 + 0][row] = pa[s2].x;
            As[ak4 * 4 + 1][row] = pa[s2].y;
            As[ak4 * 4 + 2][row] = pa[s2].z;
            As[ak4 * 4 + 3][row] = pa[s2].w;
            *(float4*)&Bs[brow + s2 * 8][bc4 * 4] = pb[s2];
        }
        __syncthreads();

        if (kt < 63) {  // prefetch next k-strip while computing this one
            const int k0 = (kt + 1) * 16;
#pragma unroll
            for (int s2 = 0; s2 < 2; ++s2) {
                pa[s2] = *(const float4*)&Aptr[(size_t)(arow + s2 * 64) * DD + k0 + ak4 * 4];
                pb[s2] = *(const float4*)&W[(size_t)(k0 + brow + s2 * 8) * DD + n0 + bc4 * 4];
            }
        }

#pragma unroll
        for (int k = 0; k < 16; ++k) {
            const float4 a0 = *(const float4*)&As[k][ty * 4];
            const float4 a1 = *(const float4*)&As[k][64 + ty * 4];
            const float4 b0 = *(const float4*)&Bs[k][tx * 4];
            const float4 b1 = *(const float4*)&Bs[k][64 + tx * 4];
            const float av[8] = {a0.x, a0.y, a0.z, a0.w, a1.x, a1.y, a1.z, a1.w};
            const float bv[8] = {b0.x, b0.y, b0.z, b0.w, b1.x, b1.y, b1.z, b1.w};
#pragma unroll
            for (int i = 0; i < 8; ++i)
#pragma unroll
                for (int j = 0; j < 8; ++j)
                    acc[i][j] = fmaf(av[i], bv[j], acc[i][j]);
        }
        __syncthreads();
    }

    // epilogue: bias + store
#pragma unroll
    for (int i = 0; i < 8; ++i) {
        const int mrow = m0 + ((i < 4) ? (ty * 4 + i) : (64 + ty * 4 + (i - 4)));
#pragma unroll
        for (int jh = 0; jh < 2; ++jh) {
            const int ncol = n0 + jh * 64 + tx * 4;
            const float4 b4 = *(const float4*)&bias[ncol];
            float4 r;
            r.x = acc[i][jh * 4 + 0] + b4.x;
            r.y = acc[i][jh * 4 + 1] + b4.y;
            r.z = acc[i][jh * 4 + 2] + b4.z;
            r.w = acc[i][jh * 4 + 3] + b4.w;
            if (MODE == 0) {
                const int bidx = mrow >> 11;     // / S
                const int srow = mrow & 2047;    // % S
                const int hh   = ncol >> 6;      // / HD
                const int hd   = ncol & 63;      // % HD
                *(float4*)&C[(((size_t)(bidx * HH + hh)) * SS + srow) * HD + hd] = r;
            } else {
                *(float4*)&C[(size_t)mrow * DD + ncol] = r;
            }
        }
    }
}

// ---------------------------------------------------------------------------
// Flash-style causal attention, fp32.
// Grid: (S/64, H, B).  Block: 256 threads (tx=0..15 col-chunks, ty=0..15 row-
// chunks).  Q tile 64 rows resident in LDS; iterate k-tiles of 64 (skipping
// fully-masked ones); online softmax in registers with 16-lane shfl reduces.
// ---------------------------------------------------------------------------
__global__ __launch_bounds__(256) void attn_kernel(
    const float* __restrict__ Qg, const float* __restrict__ Kg,
    const float* __restrict__ Vg, float* __restrict__ Og)
{
    __shared__ float Qs[64][68];   // [r][d]
    __shared__ float KT[64][68];   // [d][c]  (transposed K tile)
    __shared__ float Vs[64][68];   // [c][d]
    __shared__ float Ps[64][68];   // [r][c]

    const int tid = threadIdx.x;
    const int tx = tid & 15;
    const int ty = tid >> 4;
    const int qt = blockIdx.x;
    const int h  = blockIdx.y;
    const int b  = blockIdx.z;
    const int q0 = qt * 64;
    const size_t hb = ((size_t)(b * HH + h)) * SS * HD;

    // load Q tile (64 x 64)
#pragma unroll
    for (int i = 0; i < 4; ++i) {
        const int r = ty + i * 16;
        const float4 q = *(const float4*)&Qg[hb + (size_t)(q0 + r) * HD + tx * 4];
        *(float4*)&Qs[r][tx * 4] = q;
    }

    float m[4], l[4], o[4][4];
#pragma unroll
    for (int rr = 0; rr < 4; ++rr) {
        m[rr] = -INFINITY;
        l[rr] = 0.f;
#pragma unroll
        for (int j = 0; j < 4; ++j) o[rr][j] = 0.f;
    }

    for (int kt = 0; kt <= qt; ++kt) {
        const int k0 = kt * 64;
        __syncthreads();   // protect KT/Vs/Ps against previous iteration readers

        // load K (transposed into [d][c]) and V tiles
#pragma unroll
        for (int i = 0; i < 4; ++i) {
            const int c = ty + i * 16;
            const float4 kv = *(const float4*)&Kg[hb + (size_t)(k0 + c) * HD + tx * 4];
            KT[tx * 4 + 0][c] = kv.x;
            KT[tx * 4 + 1][c] = kv.y;
            KT[tx * 4 + 2][c] = kv.z;
            KT[tx * 4 + 3][c] = kv.w;
            const float4 vv = *(const float4*)&Vg[hb + (size_t)(k0 + c) * HD + tx * 4];
            *(float4*)&Vs[c][tx * 4] = vv;
        }
        __syncthreads();

        // scores: sc[rr][i] = Q[4ty+rr] . K[4tx+i]
        float sc[4][4];
#pragma unroll
        for (int rr = 0; rr < 4; ++rr)
#pragma unroll
            for (int i = 0; i < 4; ++i) sc[rr][i] = 0.f;

        for (int d = 0; d < 64; ++d) {
            const float4 kv = *(const float4*)&KT[d][tx * 4];
#pragma unroll
            for (int rr = 0; rr < 4; ++rr) {
                const float qv = Qs[ty * 4 + rr][d];
                sc[rr][0] = fmaf(qv, kv.x, sc[rr][0]);
                sc[rr][1] = fmaf(qv, kv.y, sc[rr][1]);
                sc[rr][2] = fmaf(qv, kv.z, sc[rr][2]);
                sc[rr][3] = fmaf(qv, kv.w, sc[rr][3]);
            }
        }

        const bool diag = (kt == qt);   // only the diagonal tile needs masking
#pragma unroll
        for (int rr = 0; rr < 4; ++rr) {
            const int qrow = q0 + ty * 4 + rr;
#pragma unroll
            for (int i = 0; i < 4; ++i) {
                float v = sc[rr][i] * 0.125f;   // 1/sqrt(HD)
                if (diag && (k0 + tx * 4 + i > qrow)) v = -INFINITY;
                sc[rr][i] = v;
            }
            float rmax = fmaxf(fmaxf(sc[rr][0], sc[rr][1]), fmaxf(sc[rr][2], sc[rr][3]));
#pragma unroll
            for (int off = 1; off < 16; off <<= 1)
                rmax = fmaxf(rmax, __shfl_xor(rmax, off));
            const float mnew  = fmaxf(m[rr], rmax);
            const float alpha = __expf(m[rr] - mnew);
            const float p0 = __expf(sc[rr][0] - mnew);
            const float p1 = __expf(sc[rr][1] - mnew);
            const float p2 = __expf(sc[rr][2] - mnew);
            const float p3 = __expf(sc[rr][3] - mnew);
            float psum = p0 + p1 + p2 + p3;
#pragma unroll
            for (int off = 1; off < 16; off <<= 1)
                psum += __shfl_xor(psum, off);
            l[rr] = l[rr] * alpha + psum;
            m[rr] = mnew;
            o[rr][0] *= alpha; o[rr][1] *= alpha; o[rr][2] *= alpha; o[rr][3] *= alpha;
            const float4 pv = {p0, p1, p2, p3};
            *(float4*)&Ps[ty * 4 + rr][tx * 4] = pv;
        }
        __syncthreads();

        // O += P @ V
        for (int c = 0; c < 64; ++c) {
            const float4 vv = *(const float4*)&Vs[c][tx * 4];
#pragma unroll
            for (int rr = 0; rr < 4; ++rr) {
                const float p = Ps[ty * 4 + rr][c];
                o[rr][0] = fmaf(p, vv.x, o[rr][0]);
                o[rr][1] = fmaf(p, vv.y, o[rr][1]);
                o[rr][2] = fmaf(p, vv.z, o[rr][2]);
                o[rr][3] = fmaf(p, vv.w, o[rr][3]);
            }
        }
    }

    // normalize and store in plain [M, D] layout for the output projection
#pragma unroll
    for (int rr = 0; rr < 4; ++rr) {
        const float inv = 1.0f / l[rr];
        float4 ov;
        ov.x = o[rr][0] * inv;
        ov.y = o[rr][1] * inv;
        ov.z = o[rr][2] * inv;
        ov.w = o[rr][3] * inv;
        const size_t row = (size_t)b * SS + q0 + ty * 4 + rr;
        *(float4*)&Og[row * DD + h * HD + tx * 4] = ov;
    }
}

// ---------------------------------------------------------------------------
extern "C" void kernel_launch(void* const* d_in, const int* in_sizes, int n_in,
                              void* d_out, int out_size, void* d_ws, size_t ws_size,
                              hipStream_t stream)
{
    const float* x  = (const float*)d_in[0];
    // d_in[1] = attn_mask (causal, deterministic) -- unused
    const float* Wq = (const float*)d_in[2];
    const float* bq = (const float*)d_in[3];
    const float* Wk = (const float*)d_in[4];
    const float* bk = (const float*)d_in[5];
    const float* Wv = (const float*)d_in[6];
    const float* bv = (const float*)d_in[7];
    const float* Wo = (const float*)d_in[8];
    const float* bo = (const float*)d_in[9];
    float* out = (float*)d_out;

    float* ws = (float*)d_ws;
    const size_t SZ = (size_t)MM * DD;       // 4M floats per buffer
    float* Qb = ws;
    float* Kb = ws + SZ;
    float* Vb = ws + 2 * SZ;
    float* Ab = ws + 3 * SZ;

    const dim3 blk(256);
    const dim3 gemm_grid(DD / 128, MM / 128);    // 8 x 32

    // Q/K/V projections -> [B,H,S,HD]
    sgemm_kernel<0><<<gemm_grid, blk, 0, stream>>>(x, Wq, bq, Qb);
    sgemm_kernel<0><<<gemm_grid, blk, 0, stream>>>(x, Wk, bk, Kb);
    sgemm_kernel<0><<<gemm_grid, blk, 0, stream>>>(x, Wv, bv, Vb);

    // causal flash attention -> [M, D]
    attn_kernel<<<dim3(SS / 64, HH, BB), blk, 0, stream>>>(Qb, Kb, Vb, Ab);

    // output projection -> d_out
    sgemm_kernel<1><<<gemm_grid, blk, 0, stream>>>(Ab, Wo, bo, out);
}

// Round 7
// 568.645 us; speedup vs baseline: 2.1444x; 2.1444x over previous
//
#include <hip/hip_runtime.h>
#include <math.h>

#define BB 2
#define SS 2048
#define DDIM 1024
#define HH 16
#define HD 64
#define MM (BB * SS)   // 4096 rows

typedef short s16x8 __attribute__((ext_vector_type(8)));
typedef short s16x4 __attribute__((ext_vector_type(4)));
typedef float f32x4 __attribute__((ext_vector_type(4)));
typedef unsigned int u32x4 __attribute__((ext_vector_type(4)));

// fp32 -> bf16 round-to-nearest-even (bit trick, finite values)
__device__ __forceinline__ unsigned short f2bf(float f) {
    unsigned int u = __builtin_bit_cast(unsigned int, f);
    u += 0x7fffu + ((u >> 16) & 1u);
    return (unsigned short)(u >> 16);
}
__device__ __forceinline__ float bf2f(unsigned short h) {
    return __builtin_bit_cast(float, (unsigned int)h << 16);
}

// ---------------------------------------------------------------------------
// Split-precision bf16-MFMA GEMM: C = A[M x 1024] @ W[1024 x 1024] + bias
// A,W fp32 in global; per K-tile we form Ah/Al (registers) and Bh/Bl (LDS,
// transposed [n][k], XOR-swizzled) and accumulate AhBh + AhBl + AlBh.
// MODE 0: Q' [B,H,S,128] bf16 = [hi|lo]      (split Q for attention)
// MODE 1: K  [B,H,S,64]  bf16 (hi only)
// MODE 2: V^T[B,H,64,S]  bf16 (hi only)
// MODE 3: out[M,1024] fp32
// Block: 256 thr (4 waves, 2x2 of 64x64), tile 128x128, BK=64.
// ---------------------------------------------------------------------------
template <int MODE>
__global__ __launch_bounds__(256) void proj_gemm(
    const float* __restrict__ A, const float* __restrict__ W,
    const float* __restrict__ bias, void* __restrict__ Cout)
{
    __shared__ short Bh[128][64];   // [n][k], rows 128B, slot ^= (n&7)
    __shared__ short Bl[128][64];

    const int tid  = threadIdx.x;
    const int lane = tid & 63;
    const int wave = tid >> 6;
    const int g    = lane >> 4;
    const int qq   = lane & 15;
    const int wm   = (wave >> 1) * 64;
    const int wn   = (wave & 1) * 64;
    const int n0   = blockIdx.x * 128;
    const int m0   = blockIdx.y * 128;

    f32x4 acc[4][4];
#pragma unroll
    for (int i = 0; i < 4; ++i)
#pragma unroll
        for (int j = 0; j < 4; ++j) acc[i][j] = (f32x4){0.f, 0.f, 0.f, 0.f};

    for (int kt = 0; kt < 16; ++kt) {
        const int k0 = kt * 64;
        __syncthreads();
        // ---- stage W-tile -> Bh/Bl transposed ----
#pragma unroll
        for (int uu = 0; uu < 2; ++uu) {
            const int u  = tid + uu * 256;
            const int kg = u >> 5;        // k-quad 0..15 (k = 4*kg..+3)
            const int nb = u & 31;
#pragma unroll
            for (int j = 0; j < 4; ++j) {
                const int n = nb + 32 * j;
                float v[4];
#pragma unroll
                for (int i = 0; i < 4; ++i)
                    v[i] = W[(size_t)(k0 + 4 * kg + i) * DDIM + n0 + n];
                short h4[4], l4[4];
#pragma unroll
                for (int i = 0; i < 4; ++i) {
                    const unsigned short hh = f2bf(v[i]);
                    h4[i] = (short)hh;
                    l4[i] = (short)f2bf(v[i] - bf2f(hh));
                }
                const s16x4 hv = {h4[0], h4[1], h4[2], h4[3]};
                const s16x4 lv = {l4[0], l4[1], l4[2], l4[3]};
                const int slot = (kg >> 1) ^ (n & 7);
                const int half = kg & 1;
                *(s16x4*)((char*)&Bh[0][0] + n * 128 + slot * 16 + half * 8) = hv;
                *(s16x4*)((char*)&Bl[0][0] + n * 128 + slot * 16 + half * 8) = lv;
            }
        }
        __syncthreads();

#pragma unroll
        for (int ks = 0; ks < 2; ++ks) {
            s16x8 bhf[4], blf[4];
#pragma unroll
            for (int nf = 0; nf < 4; ++nf) {
                const int n = wn + 16 * nf + qq;
                const int pslot = (4 * ks + g) ^ (n & 7);
                bhf[nf] = *(const s16x8*)((const char*)&Bh[0][0] + n * 128 + pslot * 16);
                blf[nf] = *(const s16x8*)((const char*)&Bl[0][0] + n * 128 + pslot * 16);
            }
#pragma unroll
            for (int mf = 0; mf < 4; ++mf) {
                const float* ap = &A[(size_t)(m0 + wm + 16 * mf + qq) * DDIM + k0 + ks * 32 + g * 8];
                const float4 a0 = *(const float4*)ap;
                const float4 a1 = *(const float4*)(ap + 4);
                float av[8] = {a0.x, a0.y, a0.z, a0.w, a1.x, a1.y, a1.z, a1.w};
                s16x8 ah, al;
#pragma unroll
                for (int i = 0; i < 8; ++i) {
                    const unsigned short hh = f2bf(av[i]);
                    ah[i] = (short)hh;
                    al[i] = (short)f2bf(av[i] - bf2f(hh));
                }
#pragma unroll
                for (int nf = 0; nf < 4; ++nf) {
                    acc[mf][nf] = __builtin_amdgcn_mfma_f32_16x16x32_bf16(ah, bhf[nf], acc[mf][nf], 0, 0, 0);
                    acc[mf][nf] = __builtin_amdgcn_mfma_f32_16x16x32_bf16(ah, blf[nf], acc[mf][nf], 0, 0, 0);
                    acc[mf][nf] = __builtin_amdgcn_mfma_f32_16x16x32_bf16(al, bhf[nf], acc[mf][nf], 0, 0, 0);
                }
            }
        }
    }

    // ---- epilogue ----
    float bv[4];
#pragma unroll
    for (int nf = 0; nf < 4; ++nf) bv[nf] = bias[n0 + wn + 16 * nf + qq];

#pragma unroll
    for (int mf = 0; mf < 4; ++mf) {
#pragma unroll
        for (int nf = 0; nf < 4; ++nf) {
            const int ncol = n0 + wn + 16 * nf + qq;
            if (MODE == 2) {
                // V^T: pack 4 consecutive s (regs) into one b64 store
                const int mbase = m0 + wm + 16 * mf + 4 * g;
                const int b = mbase >> 11, s = mbase & 2047;
                const int h = ncol >> 6, d = ncol & 63;
                short p4[4];
#pragma unroll
                for (int r = 0; r < 4; ++r)
                    p4[r] = (short)f2bf(acc[mf][nf][r] + bv[nf]);
                const s16x4 pv = {p4[0], p4[1], p4[2], p4[3]};
                *(s16x4*)&((short*)Cout)[(((size_t)(b * HH + h)) * HD + d) * SS + s] = pv;
            } else {
#pragma unroll
                for (int r = 0; r < 4; ++r) {
                    const int mrow = m0 + wm + 16 * mf + 4 * g + r;
                    const float val = acc[mf][nf][r] + bv[nf];
                    if (MODE == 3) {
                        ((float*)Cout)[(size_t)mrow * DDIM + ncol] = val;
                    } else {
                        const int b = mrow >> 11, s = mrow & 2047;
                        const int h = ncol >> 6, d = ncol & 63;
                        if (MODE == 0) {
                            short* Q = (short*)Cout;
                            const size_t base = (((size_t)(b * HH + h)) * SS + s) * 128;
                            const unsigned short hh = f2bf(val);
                            Q[base + d]      = (short)hh;
                            Q[base + 64 + d] = (short)f2bf(val - bf2f(hh));
                        } else { // MODE 1: K
                            ((short*)Cout)[(((size_t)(b * HH + h)) * SS + s) * 64 + d] = (short)f2bf(val);
                        }
                    }
                }
            }
        }
    }
}

// ---------------------------------------------------------------------------
// Flash attention, bf16 MFMA. Grid (32 qt, 16 h, 2 b), 256 thr (4 waves).
// Wave w owns 16 q-rows. Swapped QK^T: S^T = K_tile . Q^T so each lane owns
// one q-row (softmax via 2x shfl_xor over the 4 replica lanes). P stays in
// registers -> shuffled into PV B-frags. K/V^T tiles XOR-swizzled in LDS.
// ---------------------------------------------------------------------------
__global__ __launch_bounds__(256) void attn_mfma(
    const short* __restrict__ Qp, const short* __restrict__ Kp,
    const short* __restrict__ Vt, float* __restrict__ Ab)
{
    __shared__ short Kt[64 * 64];
    __shared__ short Vs[64 * 64];

    const int tid  = threadIdx.x;
    const int lane = tid & 63;
    const int wave = tid >> 6;
    const int g    = lane >> 4;
    const int qq   = lane & 15;
    const int qt   = 31 - blockIdx.x;      // heavy (long-k) blocks first
    const int h    = blockIdx.y;
    const int b    = blockIdx.z;
    const int q0   = qt * 64;
    const int qrow = q0 + wave * 16 + qq;

    const size_t headoff = (size_t)(b * HH + h) * SS;

    s16x8 qf[2][2];
#pragma unroll
    for (int half = 0; half < 2; ++half)
#pragma unroll
        for (int ks2 = 0; ks2 < 2; ++ks2)
            qf[half][ks2] = *(const s16x8*)&Qp[(headoff + qrow) * 128 + half * 64 + ks2 * 32 + g * 8];

    f32x4 oacc[4];
#pragma unroll
    for (int i = 0; i < 4; ++i) oacc[i] = (f32x4){0.f, 0.f, 0.f, 0.f};
    float mrun = -INFINITY, lrun = 0.f;

    for (int kt = 0; kt <= qt; ++kt) {
        const int kc0 = kt * 64;
        __syncthreads();
        // stage K-tile [64 kc][64 d] and V^T-tile [64 d][64 kc], swizzled
#pragma unroll
        for (int uu = 0; uu < 2; ++uu) {
            const int S = uu * 256 + tid;
            const int row = S >> 3, sl = S & 7;
            const int dsl = (sl ^ (row & 7)) * 8;
            const s16x8 kv = *(const s16x8*)&Kp[(headoff + kc0 + row) * 64 + sl * 8];
            *(s16x8*)&Kt[row * 64 + dsl] = kv;
            const s16x8 vv = *(const s16x8*)&Vt[((size_t)(b * HH + h) * HD + row) * SS + kc0 + sl * 8];
            *(s16x8*)&Vs[row * 64 + dsl] = vv;
        }
        __syncthreads();

        // S^T frags: sacc[kcf], kc = kcf*16 + 4g + reg, q = qq
        f32x4 sacc[4];
#pragma unroll
        for (int i = 0; i < 4; ++i) sacc[i] = (f32x4){0.f, 0.f, 0.f, 0.f};
#pragma unroll
        for (int kcf = 0; kcf < 4; ++kcf) {
            const int row = kcf * 16 + qq;
            s16x8 kf[2];
#pragma unroll
            for (int ks2 = 0; ks2 < 2; ++ks2)
                kf[ks2] = *(const s16x8*)&Kt[row * 64 + (((ks2 * 4 + g) ^ (row & 7)) * 8)];
#pragma unroll
            for (int half = 0; half < 2; ++half)
#pragma unroll
                for (int ks2 = 0; ks2 < 2; ++ks2)
                    sacc[kcf] = __builtin_amdgcn_mfma_f32_16x16x32_bf16(kf[ks2], qf[half][ks2], sacc[kcf], 0, 0, 0);
        }

        // online softmax (each lane owns row qq; replicas at lane^16, lane^32)
        float sc[16];
        float pmax = -INFINITY;
#pragma unroll
        for (int kcf = 0; kcf < 4; ++kcf)
#pragma unroll
            for (int r = 0; r < 4; ++r) {
                float v = sacc[kcf][r] * 0.125f;
                const int kc = kc0 + kcf * 16 + g * 4 + r;
                if (kc > qrow) v = -INFINITY;
                sc[kcf * 4 + r] = v;
                pmax = fmaxf(pmax, v);
            }
        pmax = fmaxf(pmax, __shfl_xor(pmax, 16));
        pmax = fmaxf(pmax, __shfl_xor(pmax, 32));
        const float mnew  = fmaxf(mrun, pmax);
        const float alpha = __expf(mrun - mnew);
        float p[16], psum = 0.f;
#pragma unroll
        for (int i = 0; i < 16; ++i) { p[i] = __expf(sc[i] - mnew); psum += p[i]; }
        psum += __shfl_xor(psum, 16);
        psum += __shfl_xor(psum, 32);
        lrun = lrun * alpha + psum;
        mrun = mnew;
#pragma unroll
        for (int df = 0; df < 4; ++df) oacc[df] *= alpha;

        // pack P to bf16 pairs: pk[kcf][hh] = (kc 16kcf+4g+2hh, +1)
        unsigned int pk[4][2];
#pragma unroll
        for (int kcf = 0; kcf < 4; ++kcf)
#pragma unroll
            for (int hh = 0; hh < 2; ++hh)
                pk[kcf][hh] = (unsigned int)f2bf(p[kcf * 4 + 2 * hh]) |
                              ((unsigned int)f2bf(p[kcf * 4 + 2 * hh + 1]) << 16);

        // redistribute into PV B-frags: lane needs P^T[kc=8g+2w+32ks][q=qq]
        s16x8 pb[2];
#pragma unroll
        for (int ks = 0; ks < 2; ++ks) {
            unsigned int w_[4];
#pragma unroll
            for (int w = 0; w < 2 * 2; ++w) {
                const int gs  = (2 * g + (w >> 1)) & 3;
                const int src = qq | (gs << 4);
                const unsigned int va = (unsigned int)__shfl((int)pk[2 * ks][w & 1], src);
                const unsigned int vb = (unsigned int)__shfl((int)pk[2 * ks + 1][w & 1], src);
                w_[w] = (g & 2) ? vb : va;
            }
            const u32x4 t = {w_[0], w_[1], w_[2], w_[3]};
            pb[ks] = __builtin_bit_cast(s16x8, t);
        }

        // O^T += V^T . P^T
#pragma unroll
        for (int df = 0; df < 4; ++df) {
            const int row = df * 16 + qq;
#pragma unroll
            for (int ks = 0; ks < 2; ++ks) {
                const s16x8 vf = *(const s16x8*)&Vs[row * 64 + (((ks * 4 + g) ^ (row & 7)) * 8)];
                oacc[df] = __builtin_amdgcn_mfma_f32_16x16x32_bf16(vf, pb[ks], oacc[df], 0, 0, 0);
            }
        }
    }

    const float inv = 1.0f / lrun;
#pragma unroll
    for (int df = 0; df < 4; ++df) {
        f32x4 r = oacc[df];
        r *= inv;
        *(f32x4*)&Ab[((size_t)b * SS + qrow) * DDIM + h * HD + df * 16 + g * 4] = r;
    }
}

// ---------------------------------------------------------------------------
extern "C" void kernel_launch(void* const* d_in, const int* in_sizes, int n_in,
                              void* d_out, int out_size, void* d_ws, size_t ws_size,
                              hipStream_t stream)
{
    const float* x  = (const float*)d_in[0];
    const float* Wq = (const float*)d_in[2];
    const float* bq = (const float*)d_in[3];
    const float* Wk = (const float*)d_in[4];
    const float* bk = (const float*)d_in[5];
    const float* Wv = (const float*)d_in[6];
    const float* bv = (const float*)d_in[7];
    const float* Wo = (const float*)d_in[8];
    const float* bo = (const float*)d_in[9];
    float* out = (float*)d_out;

    char* w = (char*)d_ws;
    short* Qp = (short*)w;                               // 16 MiB  [B,H,S,128]
    short* Kp = (short*)(w + (size_t)16 * 1024 * 1024);  //  8 MiB  [B,H,S,64]
    short* Vt = (short*)(w + (size_t)24 * 1024 * 1024);  //  8 MiB  [B,H,64,S]
    float* Ab = (float*)(w + (size_t)32 * 1024 * 1024);  // 16 MiB  [M,1024]

    const dim3 blk(256);
    const dim3 gg(DDIM / 128, MM / 128);   // 8 x 32 = 256 blocks

    proj_gemm<0><<<gg, blk, 0, stream>>>(x, Wq, bq, (void*)Qp);
    proj_gemm<1><<<gg, blk, 0, stream>>>(x, Wk, bk, (void*)Kp);
    proj_gemm<2><<<gg, blk, 0, stream>>>(x, Wv, bv, (void*)Vt);

    attn_mfma<<<dim3(32, HH, BB), blk, 0, stream>>>(Qp, Kp, Vt, Ab);

    proj_gemm<3><<<gg, blk, 0, stream>>>(Ab, Wo, bo, (void*)out);
}

// Round 9
// 498.376 us; speedup vs baseline: 2.4468x; 1.1410x over previous
//
#include <hip/hip_runtime.h>
#include <math.h>

#define BB 2
#define SS 2048
#define DDIM 1024
#define HH 16
#define HD 64
#define MM (BB * SS)   // 4096 rows

typedef short s16x8 __attribute__((ext_vector_type(8)));
typedef short s16x4 __attribute__((ext_vector_type(4)));
typedef float f32x4 __attribute__((ext_vector_type(4)));
typedef unsigned int u32x4 __attribute__((ext_vector_type(4)));

// fp32 -> bf16 round-to-nearest-even (bit trick, finite values)
__device__ __forceinline__ unsigned short f2bf(float f) {
    unsigned int u = __builtin_bit_cast(unsigned int, f);
    u += 0x7fffu + ((u >> 16) & 1u);
    return (unsigned short)(u >> 16);
}
__device__ __forceinline__ float bf2f(unsigned short h) {
    return __builtin_bit_cast(float, (unsigned int)h << 16);
}

// ---------------------------------------------------------------------------
// wsplit: W[k][n] f32  ->  WtH/WtL [z][n][k] bf16 (transposed hi/lo split).
// 64x64 tiles via LDS. Grid (16 n-tiles, 16 k-tiles, 4 matrices).
// ---------------------------------------------------------------------------
__global__ __launch_bounds__(256) void wsplit(
    const float* __restrict__ W0, const float* __restrict__ W1,
    const float* __restrict__ W2, const float* __restrict__ W3,
    short* __restrict__ WtH, short* __restrict__ WtL)
{
    __shared__ float T[64][65];
    const int z  = blockIdx.z;
    const float* W = (z == 0) ? W0 : (z == 1) ? W1 : (z == 2) ? W2 : W3;
    const int n0 = blockIdx.x * 64;
    const int k0 = blockIdx.y * 64;
    const int t  = threadIdx.x;

    // load 64(k) x 64(n), coalesced rows
#pragma unroll
    for (int i = 0; i < 4; ++i) {
        const int kr = (t >> 4) + i * 16;
        const int c4 = (t & 15) * 4;
        const float4 v = *(const float4*)&W[(size_t)(k0 + kr) * DDIM + n0 + c4];
        T[kr][c4 + 0] = v.x; T[kr][c4 + 1] = v.y;
        T[kr][c4 + 2] = v.z; T[kr][c4 + 3] = v.w;
    }
    __syncthreads();

    // write transposed: thread t -> out row n = t>>2, k-chunk = (t&3)*16
    const int n  = t >> 2;
    const int kb = (t & 3) * 16;
    s16x8 h0, h1, l0, l1;
#pragma unroll
    for (int j = 0; j < 8; ++j) {
        const float f0 = T[kb + j][n];
        const unsigned short hh0 = f2bf(f0);
        h0[j] = (short)hh0; l0[j] = (short)f2bf(f0 - bf2f(hh0));
        const float f1 = T[kb + 8 + j][n];
        const unsigned short hh1 = f2bf(f1);
        h1[j] = (short)hh1; l1[j] = (short)f2bf(f1 - bf2f(hh1));
    }
    const size_t ob = ((size_t)z * DDIM + n0 + n) * DDIM + k0 + kb;
    *(s16x8*)&WtH[ob]     = h0;
    *(s16x8*)&WtH[ob + 8] = h1;
    *(s16x8*)&WtL[ob]     = l0;
    *(s16x8*)&WtL[ob + 8] = l1;
}

// ---------------------------------------------------------------------------
// proj_v2: C = A[M x 1024](f32, split in-register) @ W(pre-split bf16 [n][k])
//          + bias, 3-pass split accumulation (AhBh + AhBl + AlBh).
// Tile 64x64, BK=64, 4 waves (2x2), wave-tile 32x32 (2x2 16x16 frags).
// Grid 16 x 64 = 1024 blocks -> 4 blocks/CU, 16 waves/CU.
// B staged in LDS hi/lo with XOR swizzle (store c^(r&7), read (4ks+g)^(qq&7)).
// MODE 0: Q' [B,H,S,128] bf16 hi|lo   MODE 1: K [B,H,S,64] bf16
// MODE 2: V^T [B,H,64,S] bf16         MODE 3: out [M,1024] f32
// ---------------------------------------------------------------------------
template <int MODE>
__global__ __launch_bounds__(256) void proj_v2(
    const float* __restrict__ A, const short* __restrict__ BTh,
    const short* __restrict__ BTl, const float* __restrict__ bias,
    void* __restrict__ Cout)
{
    __shared__ short Bh[64 * 64];
    __shared__ short Bl[64 * 64];

    const int tid  = threadIdx.x;
    const int lane = tid & 63;
    const int wave = tid >> 6;
    const int g    = lane >> 4;
    const int qq   = lane & 15;
    const int wm   = (wave >> 1) * 32;
    const int wn   = (wave & 1) * 32;
    const int n0   = blockIdx.x * 64;
    const int m0   = blockIdx.y * 64;

    // staging: thread -> row sr (n), chunk pair sc
    const int sr = tid >> 2;
    const int sc = (tid & 3) * 2;
    const int d0 = sr * 64 + ((sc ^ (sr & 7)) * 8);
    const int d1 = sr * 64 + (((sc + 1) ^ (sr & 7)) * 8);

    f32x4 acc[2][2];
#pragma unroll
    for (int i = 0; i < 2; ++i)
#pragma unroll
        for (int j = 0; j < 2; ++j) acc[i][j] = (f32x4){0.f, 0.f, 0.f, 0.f};

    for (int kt = 0; kt < 16; ++kt) {
        const int k0 = kt * 64;
        __syncthreads();
        {
            const size_t gb = (size_t)(n0 + sr) * DDIM + k0 + sc * 8;
            const s16x8 h0 = *(const s16x8*)&BTh[gb];
            const s16x8 h1 = *(const s16x8*)&BTh[gb + 8];
            const s16x8 l0 = *(const s16x8*)&BTl[gb];
            const s16x8 l1 = *(const s16x8*)&BTl[gb + 8];
            *(s16x8*)&Bh[d0] = h0;
            *(s16x8*)&Bh[d1] = h1;
            *(s16x8*)&Bl[d0] = l0;
            *(s16x8*)&Bl[d1] = l1;
        }
        __syncthreads();

#pragma unroll
        for (int ks = 0; ks < 2; ++ks) {
            s16x8 bhf[2], blf[2];
#pragma unroll
            for (int nf = 0; nf < 2; ++nf) {
                const int r  = wn + 16 * nf + qq;
                const int ch = (((ks * 4 + g) ^ (qq & 7)) * 8);
                bhf[nf] = *(const s16x8*)&Bh[r * 64 + ch];
                blf[nf] = *(const s16x8*)&Bl[r * 64 + ch];
            }
#pragma unroll
            for (int mf = 0; mf < 2; ++mf) {
                const float* ap = &A[(size_t)(m0 + wm + 16 * mf + qq) * DDIM + k0 + ks * 32 + g * 8];
                const float4 a0 = *(const float4*)ap;
                const float4 a1 = *(const float4*)(ap + 4);
                const float av[8] = {a0.x, a0.y, a0.z, a0.w, a1.x, a1.y, a1.z, a1.w};
                s16x8 ah, al;
#pragma unroll
                for (int i = 0; i < 8; ++i) {
                    const unsigned short hh = f2bf(av[i]);
                    ah[i] = (short)hh;
                    al[i] = (short)f2bf(av[i] - bf2f(hh));
                }
#pragma unroll
                for (int nf = 0; nf < 2; ++nf) {
                    acc[mf][nf] = __builtin_amdgcn_mfma_f32_16x16x32_bf16(ah, bhf[nf], acc[mf][nf], 0, 0, 0);
                    acc[mf][nf] = __builtin_amdgcn_mfma_f32_16x16x32_bf16(ah, blf[nf], acc[mf][nf], 0, 0, 0);
                    acc[mf][nf] = __builtin_amdgcn_mfma_f32_16x16x32_bf16(al, bhf[nf], acc[mf][nf], 0, 0, 0);
                }
            }
        }
    }

    // ---- epilogue ----
    float bv2[2];
#pragma unroll
    for (int nf = 0; nf < 2; ++nf) bv2[nf] = bias[n0 + wn + 16 * nf + qq];

#pragma unroll
    for (int mf = 0; mf < 2; ++mf) {
#pragma unroll
        for (int nf = 0; nf < 2; ++nf) {
            const int ncol = n0 + wn + 16 * nf + qq;
            if (MODE == 2) {
                const int mbase = m0 + wm + 16 * mf + 4 * g;
                const int b = mbase >> 11, s = mbase & 2047;
                const int h = ncol >> 6, d = ncol & 63;
                short p4[4];
#pragma unroll
                for (int r = 0; r < 4; ++r)
                    p4[r] = (short)f2bf(acc[mf][nf][r] + bv2[nf]);
                const s16x4 pv = {p4[0], p4[1], p4[2], p4[3]};
                *(s16x4*)&((short*)Cout)[(((size_t)(b * HH + h)) * HD + d) * SS + s] = pv;
            } else {
#pragma unroll
                for (int r = 0; r < 4; ++r) {
                    const int mrow = m0 + wm + 16 * mf + 4 * g + r;
                    const float val = acc[mf][nf][r] + bv2[nf];
                    if (MODE == 3) {
                        ((float*)Cout)[(size_t)mrow * DDIM + ncol] = val;
                    } else {
                        const int b = mrow >> 11, s = mrow & 2047;
                        const int h = ncol >> 6, d = ncol & 63;
                        if (MODE == 0) {
                            short* Q = (short*)Cout;
                            const size_t base = (((size_t)(b * HH + h)) * SS + s) * 128;
                            const unsigned short hh = f2bf(val);
                            Q[base + d]      = (short)hh;
                            Q[base + 64 + d] = (short)f2bf(val - bf2f(hh));
                        } else { // MODE 1: K
                            ((short*)Cout)[(((size_t)(b * HH + h)) * SS + s) * 64 + d] = (short)f2bf(val);
                        }
                    }
                }
            }
        }
    }
}

// ---------------------------------------------------------------------------
// Flash attention, bf16 MFMA (UNCHANGED from passing R7 kernel).
// ---------------------------------------------------------------------------
__global__ __launch_bounds__(256) void attn_mfma(
    const short* __restrict__ Qp, const short* __restrict__ Kp,
    const short* __restrict__ Vt, float* __restrict__ Ab)
{
    __shared__ short Kt[64 * 64];
    __shared__ short Vs[64 * 64];

    const int tid  = threadIdx.x;
    const int lane = tid & 63;
    const int wave = tid >> 6;
    const int g    = lane >> 4;
    const int qq   = lane & 15;
    const int qt   = 31 - blockIdx.x;      // heavy (long-k) blocks first
    const int h    = blockIdx.y;
    const int b    = blockIdx.z;
    const int q0   = qt * 64;
    const int qrow = q0 + wave * 16 + qq;

    const size_t headoff = (size_t)(b * HH + h) * SS;

    s16x8 qf[2][2];
#pragma unroll
    for (int half = 0; half < 2; ++half)
#pragma unroll
        for (int ks2 = 0; ks2 < 2; ++ks2)
            qf[half][ks2] = *(const s16x8*)&Qp[(headoff + qrow) * 128 + half * 64 + ks2 * 32 + g * 8];

    f32x4 oacc[4];
#pragma unroll
    for (int i = 0; i < 4; ++i) oacc[i] = (f32x4){0.f, 0.f, 0.f, 0.f};
    float mrun = -INFINITY, lrun = 0.f;

    for (int kt = 0; kt <= qt; ++kt) {
        const int kc0 = kt * 64;
        __syncthreads();
#pragma unroll
        for (int uu = 0; uu < 2; ++uu) {
            const int S = uu * 256 + tid;
            const int row = S >> 3, sl = S & 7;
            const int dsl = (sl ^ (row & 7)) * 8;
            const s16x8 kv = *(const s16x8*)&Kp[(headoff + kc0 + row) * 64 + sl * 8];
            *(s16x8*)&Kt[row * 64 + dsl] = kv;
            const s16x8 vv = *(const s16x8*)&Vt[((size_t)(b * HH + h) * HD + row) * SS + kc0 + sl * 8];
            *(s16x8*)&Vs[row * 64 + dsl] = vv;
        }
        __syncthreads();

        f32x4 sacc[4];
#pragma unroll
        for (int i = 0; i < 4; ++i) sacc[i] = (f32x4){0.f, 0.f, 0.f, 0.f};
#pragma unroll
        for (int kcf = 0; kcf < 4; ++kcf) {
            const int row = kcf * 16 + qq;
            s16x8 kf[2];
#pragma unroll
            for (int ks2 = 0; ks2 < 2; ++ks2)
                kf[ks2] = *(const s16x8*)&Kt[row * 64 + (((ks2 * 4 + g) ^ (row & 7)) * 8)];
#pragma unroll
            for (int half = 0; half < 2; ++half)
#pragma unroll
                for (int ks2 = 0; ks2 < 2; ++ks2)
                    sacc[kcf] = __builtin_amdgcn_mfma_f32_16x16x32_bf16(kf[ks2], qf[half][ks2], sacc[kcf], 0, 0, 0);
        }

        float sc[16];
        float pmax = -INFINITY;
#pragma unroll
        for (int kcf = 0; kcf < 4; ++kcf)
#pragma unroll
            for (int r = 0; r < 4; ++r) {
                float v = sacc[kcf][r] * 0.125f;
                const int kc = kc0 + kcf * 16 + g * 4 + r;
                if (kc > qrow) v = -INFINITY;
                sc[kcf * 4 + r] = v;
                pmax = fmaxf(pmax, v);
            }
        pmax = fmaxf(pmax, __shfl_xor(pmax, 16));
        pmax = fmaxf(pmax, __shfl_xor(pmax, 32));
        const float mnew  = fmaxf(mrun, pmax);
        const float alpha = __expf(mrun - mnew);
        float p[16], psum = 0.f;
#pragma unroll
        for (int i = 0; i < 16; ++i) { p[i] = __expf(sc[i] - mnew); psum += p[i]; }
        psum += __shfl_xor(psum, 16);
        psum += __shfl_xor(psum, 32);
        lrun = lrun * alpha + psum;
        mrun = mnew;
#pragma unroll
        for (int df = 0; df < 4; ++df) oacc[df] *= alpha;

        unsigned int pk[4][2];
#pragma unroll
        for (int kcf = 0; kcf < 4; ++kcf)
#pragma unroll
            for (int hh = 0; hh < 2; ++hh)
                pk[kcf][hh] = (unsigned int)f2bf(p[kcf * 4 + 2 * hh]) |
                              ((unsigned int)f2bf(p[kcf * 4 + 2 * hh + 1]) << 16);

        s16x8 pb[2];
#pragma unroll
        for (int ks = 0; ks < 2; ++ks) {
            unsigned int w_[4];
#pragma unroll
            for (int w = 0; w < 2 * 2; ++w) {
                const int gs  = (2 * g + (w >> 1)) & 3;
                const int src = qq | (gs << 4);
                const unsigned int va = (unsigned int)__shfl((int)pk[2 * ks][w & 1], src);
                const unsigned int vb = (unsigned int)__shfl((int)pk[2 * ks + 1][w & 1], src);
                w_[w] = (g & 2) ? vb : va;
            }
            const u32x4 t = {w_[0], w_[1], w_[2], w_[3]};
            pb[ks] = __builtin_bit_cast(s16x8, t);
        }

#pragma unroll
        for (int df = 0; df < 4; ++df) {
            const int row = df * 16 + qq;
#pragma unroll
            for (int ks = 0; ks < 2; ++ks) {
                const s16x8 vf = *(const s16x8*)&Vs[row * 64 + (((ks * 4 + g) ^ (row & 7)) * 8)];
                oacc[df] = __builtin_amdgcn_mfma_f32_16x16x32_bf16(vf, pb[ks], oacc[df], 0, 0, 0);
            }
        }
    }

    const float inv = 1.0f / lrun;
#pragma unroll
    for (int df = 0; df < 4; ++df) {
        f32x4 r = oacc[df];
        r *= inv;
        *(f32x4*)&Ab[((size_t)b * SS + qrow) * DDIM + h * HD + df * 16 + g * 4] = r;
    }
}

// ---------------------------------------------------------------------------
extern "C" void kernel_launch(void* const* d_in, const int* in_sizes, int n_in,
                              void* d_out, int out_size, void* d_ws, size_t ws_size,
                              hipStream_t stream)
{
    const float* x  = (const float*)d_in[0];
    const float* Wq = (const float*)d_in[2];
    const float* bq = (const float*)d_in[3];
    const float* Wk = (const float*)d_in[4];
    const float* bk = (const float*)d_in[5];
    const float* Wv = (const float*)d_in[6];
    const float* bv = (const float*)d_in[7];
    const float* Wo = (const float*)d_in[8];
    const float* bo = (const float*)d_in[9];
    float* out = (float*)d_out;

    // d_ws: 48 MiB total (proven size).  Qp lives in d_out (16 MiB):
    // written by proj<0> (disp 2), read by attn (disp 5), overwritten by
    // proj<3> (disp 6) -- stream-serialized, no overlap.
    char* w = (char*)d_ws;
    short* Kp  = (short*)w;                               //  8 MiB [B,H,S,64]
    short* Vt  = (short*)(w + (size_t) 8 * 1024 * 1024);  //  8 MiB [B,H,64,S]
    float* Ab  = (float*)(w + (size_t)16 * 1024 * 1024);  // 16 MiB [M,1024] f32
    short* WtH = (short*)(w + (size_t)32 * 1024 * 1024);  //  8 MiB [4][n][k]
    short* WtL = (short*)(w + (size_t)40 * 1024 * 1024);  //  8 MiB [4][n][k]
    short* Qp  = (short*)d_out;                           // 16 MiB [B,H,S,128]

    const dim3 blk(256);
    const dim3 gg(DDIM / 64, MM / 64);   // 16 x 64 = 1024 blocks

    wsplit<<<dim3(16, 16, 4), blk, 0, stream>>>(Wq, Wk, Wv, Wo, WtH, WtL);

    proj_v2<0><<<gg, blk, 0, stream>>>(x,  WtH + (size_t)0 * 1048576, WtL + (size_t)0 * 1048576, bq, (void*)Qp);
    proj_v2<1><<<gg, blk, 0, stream>>>(x,  WtH + (size_t)1 * 1048576, WtL + (size_t)1 * 1048576, bk, (void*)Kp);
    proj_v2<2><<<gg, blk, 0, stream>>>(x,  WtH + (size_t)2 * 1048576, WtL + (size_t)2 * 1048576, bv, (void*)Vt);

    attn_mfma<<<dim3(32, HH, BB), blk, 0, stream>>>(Qp, Kp, Vt, Ab);

    proj_v2<3><<<gg, blk, 0, stream>>>(Ab, WtH + (size_t)3 * 1048576, WtL + (size_t)3 * 1048576, bo, (void*)out);
}